// Round 11
// baseline (198.389 us; speedup 1.0000x reference)
//
#include <hip/hip_runtime.h>
#include <hip/hip_bf16.h>

// ---- problem constants (match reference) ----
#define HIN   721
#define WIN   1440
#define HOUT_ 361
#define WOUT_ 720
#define NB    4
#define CIN_  8
#define COUT_ 32
#define KT    9
#define NNZ_  32
// derived: PSCALE = 2, base_row(x) = 2x exactly, cols in [0,16)
// q = c*10 + 2s + e  (80 values), j = col>>1 (8 values)

typedef short  bsh8   __attribute__((ext_vector_type(8)));   // 8 bf16 (4 VGPR) MFMA frag
typedef float  f32x16 __attribute__((ext_vector_type(16)));  // 32x32 MFMA acc
typedef unsigned int u32x4 __attribute__((ext_vector_type(4)));

static __device__ __forceinline__ unsigned short f2bf(float f) {
  unsigned u = __builtin_bit_cast(unsigned, f);
  u += 0x7fffu + ((u >> 16) & 1u);      // RNE
  return (unsigned short)(u >> 16);
}

static __device__ __forceinline__ unsigned pack2(float a, float b) {
  __hip_bfloat162 h = __float22bfloat162_rn(make_float2(a, b));
  unsigned u; __builtin_memcpy(&u, &h, 4);
  return u;                              // a -> low 16, b -> high 16
}

// =====================================================================
// K1: build combined coefficients — LDS-slimmed for 3 blocks/CU so all
// 361 blocks are co-resident (was 95KB -> 1 block/CU -> 2 serial rounds).
//  - Cl stored as bf16 (identical rounding: conversion moved from
//    writeback to combine-write), stride 83 u16.
//  - weight read direct from global (9 floats/thread, once) — no wl.
//  LDS = 256*83*2 + 9*80*4 = 45376 B.
// =====================================================================
__global__ __launch_bounds__(256, 3) void coeff_kernel(
    const int*   __restrict__ psi_idx,
    const float* __restrict__ psi_vals,
    const float* __restrict__ weight,
    unsigned short* __restrict__ Cg)
{
  __shared__ unsigned short Cl16[256 * 83];   // 42496 B
  __shared__ float S[KT][80];                 // 2880 B

  const int x = blockIdx.x, tid = threadIdx.x;

  for (int i = tid; i < KT * 80; i += 256) ((float*)S)[i] = 0.f;
  __syncthreads();

  for (int i = tid; i < KT * NNZ_; i += 256) {   // scatter all 288 taps
    int k = i >> 5, n = i & 31;
    int gi  = (k * HOUT_ + x) * NNZ_ + n;
    int idx = psi_idx[gi];
    int r   = idx / WIN;
    int col = idx - r * WIN;               // in [0,16)
    int s   = r - 2 * x + 2;               // in [0,4] after reference clip
    int slot = (s * 2 + (col & 1)) * 8 + (col >> 1);
    atomicAdd(&S[k][slot], psi_vals[gi]);
  }

  // thread (o = tid>>3, c = tid&7) reads its own 9 weights from global
  float w[KT];
  #pragma unroll
  for (int k = 0; k < KT; ++k) w[k] = weight[tid * KT + k];
  __syncthreads();

  { // dense combine, bf16 write
    unsigned short* seg = &Cl16[tid * 83];
    #pragma unroll
    for (int slot = 0; slot < 80; ++slot) {
      float acc = 0.f;
      #pragma unroll
      for (int k = 0; k < KT; ++k) acc += w[k] * S[k][slot];
      seg[slot] = f2bf(acc);
    }
  }
  __syncthreads();

  // writeback as 16B chunks: Cg[((x*8+j)*10+qb)*32+o][qi0..7]
  for (int chunk = tid; chunk < 8 * 10 * 32; chunk += 256) {
    int j   = chunk / 320;
    int rem = chunk - j * 320;
    int qb  = rem >> 5, o = rem & 31;
    u32x4 pack;
    #pragma unroll
    for (int h = 0; h < 4; ++h) {
      int q0 = qb * 8 + 2 * h;
      int c0 = q0 / 10, ql0 = q0 - c0 * 10;
      int q1 = q0 + 1;
      int c1 = q1 / 10, ql1 = q1 - c1 * 10;
      unsigned lo = Cl16[(o * CIN_ + c0) * 83 + ql0 * 8 + j];
      unsigned hi = Cl16[(o * CIN_ + c1) * 83 + ql1 * 8 + j];
      pack[h] = lo | (hi << 16);
    }
    *(u32x4*)&Cg[((size_t)x * 2560 + (size_t)((j * 10 + qb) * 32 + o)) * 8] = pack;
  }
}

// =====================================================================
// K2: main compute. R8 body (best known: PB=256, RST=176 bank-floor
// layout, depth-2 a-frag prefetch, nontemporal stores) wrapped in a
// 3-item pt-loop per block: block = (xo, b), items pt = 0..2.
//  - items share the 40KB Cg[xo] slice -> items 2,3 a-frag loads are
//    L1-hot; decode + rr setup amortized 3x.
//  - grid 1444 = 361*4, bijective m204 XCD chunking (q=180, r=4).
// =====================================================================
#define PB   256
#define ROWS 264            // max row read = 262
#define RST  176            // 176 mod 128 = 48 -> b128 reads at bank floor

__global__ __launch_bounds__(256, 3) void disco_main_kernel(
    const float* __restrict__ x,
    const unsigned short* __restrict__ Cg,
    float* __restrict__ out)
{
  __shared__ __align__(16) unsigned char Ut[ROWS * RST];  // 46464 B

  // ---- bijective XCD-chunked decode (nwg = 1444 = 8*180 + 4, m204) ----
  const int g   = blockIdx.x;
  const int xcd = g & 7, lin = g >> 3;
  const int swz = (xcd < 4) ? xcd * 181 + lin : 724 + (xcd - 4) * 180 + lin;
  const int xo  = swz >> 2;         // 0..360
  const int b   = swz & 3;          // 0..3
  const int tid = threadIdx.x;

  const int lane = tid & 63;
  const int wv   = tid >> 6;        // 0..3: 64-wide p slice
  const int half = lane >> 5;       // k-slice half (chunk parity)
  const int l31  = lane & 31;
  const int wbase = wv * 64;

  const unsigned short* cgx = Cg + (size_t)xo * 2560 * 8
                                 + (size_t)(half * 32 + l31) * 8;
  const float* xb = x + (size_t)b * (CIN_ * HIN * WIN);

  int rr[5];
  #pragma unroll
  for (int s = 0; s < 5; ++s) {
    int r = 2 * xo + s - 2;
    rr[s] = r < 0 ? 0 : (r > HIN - 1 ? HIN - 1 : r);
  }

  for (int pt = 0; pt < 3; ++pt) {
    const int p0 = pt * PB;
    if (pt) __syncthreads();        // prior item's reads done before overwrite

    // ---- j=0 / j=1 A-frags issued first (L1-hot for pt>0) ----
    bsh8 a0[5], a1[5];
    #pragma unroll
    for (int kb = 0; kb < 5; ++kb) a0[kb] = *(const bsh8*)&cgx[kb * 512];
    #pragma unroll
    for (int kb = 0; kb < 5; ++kb) a1[kb] = *(const bsh8*)&cgx[2560 + kb * 512];

    // ---- stage Ut: 1320 units (ch = u/132, rp = u%132 -> rows 2rp,2rp+1) ----
    #pragma unroll
    for (int bp = 0; bp < 2; ++bp) {
      float4 v0[4], v1[4];
      const int uA = tid + (2 * bp) * 256, uB = uA + 256;
      const int chA = uA / 132, rpA = uA - chA * 132;
      const int chB = uB / 132, rpB = uB - chB * 132;
      int cwA = p0 + 2 * rpA; if (cwA >= WOUT_) cwA -= WOUT_;
      int cwB = p0 + 2 * rpB; if (cwB >= WOUT_) cwB -= WOUT_;
      #pragma unroll
      for (int m = 0; m < 4; ++m) {
        int qpA = 4 * chA + m, cA = (qpA * 205) >> 10, sA = qpA - cA * 5;
        v0[m] = *(const float4*)&xb[(size_t)(cA * HIN + rr[sA]) * WIN + 2 * cwA];
        int qpB = 4 * chB + m, cB = (qpB * 205) >> 10, sB = qpB - cB * 5;
        v1[m] = *(const float4*)&xb[(size_t)(cB * HIN + rr[sB]) * WIN + 2 * cwB];
      }
      u32x4 lo, hi;
      #pragma unroll
      for (int m = 0; m < 4; ++m) { lo[m] = pack2(v0[m].x, v0[m].y); hi[m] = pack2(v0[m].z, v0[m].w); }
      int byte0 = (2 * rpA) * RST + chA * 16;
      *(u32x4*)&Ut[byte0]       = lo;
      *(u32x4*)&Ut[byte0 + RST] = hi;
      #pragma unroll
      for (int m = 0; m < 4; ++m) { lo[m] = pack2(v1[m].x, v1[m].y); hi[m] = pack2(v1[m].z, v1[m].w); }
      byte0 = (2 * rpB) * RST + chB * 16;
      *(u32x4*)&Ut[byte0]       = lo;
      *(u32x4*)&Ut[byte0 + RST] = hi;
    }
    { // unit pass 5 (u in [1024,1280)) + tail (u in [1280,1320), tid < 40)
      const int uA = tid + 1024;
      const int chA = uA / 132, rpA = uA - chA * 132;
      int cwA = p0 + 2 * rpA; if (cwA >= WOUT_) cwA -= WOUT_;
      float4 v0[4], v1[4];
      int chB = 0, rpB = 0;
      const bool tail = tid < 40;
      if (tail) {
        const int uB = tid + 1280;
        chB = uB / 132; rpB = uB - chB * 132;
      }
      int cwB = p0 + 2 * rpB; if (cwB >= WOUT_) cwB -= WOUT_;
      #pragma unroll
      for (int m = 0; m < 4; ++m) {
        int qpA = 4 * chA + m, cA = (qpA * 205) >> 10, sA = qpA - cA * 5;
        v0[m] = *(const float4*)&xb[(size_t)(cA * HIN + rr[sA]) * WIN + 2 * cwA];
      }
      if (tail) {
        #pragma unroll
        for (int m = 0; m < 4; ++m) {
          int qpB = 4 * chB + m, cB = (qpB * 205) >> 10, sB = qpB - cB * 5;
          v1[m] = *(const float4*)&xb[(size_t)(cB * HIN + rr[sB]) * WIN + 2 * cwB];
        }
      }
      u32x4 lo, hi;
      #pragma unroll
      for (int m = 0; m < 4; ++m) { lo[m] = pack2(v0[m].x, v0[m].y); hi[m] = pack2(v0[m].z, v0[m].w); }
      int byte0 = (2 * rpA) * RST + chA * 16;
      *(u32x4*)&Ut[byte0]       = lo;
      *(u32x4*)&Ut[byte0 + RST] = hi;
      if (tail) {
        #pragma unroll
        for (int m = 0; m < 4; ++m) { lo[m] = pack2(v1[m].x, v1[m].y); hi[m] = pack2(v1[m].z, v1[m].w); }
        byte0 = (2 * rpB) * RST + chB * 16;
        *(u32x4*)&Ut[byte0]       = lo;
        *(u32x4*)&Ut[byte0 + RST] = hi;
      }
    }
    __syncthreads();

    // ---- MFMA: wave -> 32(o) x 64(p), j unrolled, depth-2 prefetch ----
    f32x16 acc0 = {};
    f32x16 acc1 = {};

    #pragma unroll
    for (int j = 0; j < 8; ++j) {
      bsh8 a2[5];
      if (j < 6) {
        #pragma unroll
        for (int kb = 0; kb < 5; ++kb)
          a2[kb] = *(const bsh8*)&cgx[(j + 2) * 2560 + kb * 512];
      }
      const int rb0 = (wbase + l31 + j) * RST;
      const int rb1 = rb0 + 32 * RST;
      #pragma unroll
      for (int kb = 0; kb < 5; ++kb) {
        const int cho = (2 * kb + half) * 16;
        bsh8 b0 = *(const bsh8*)&Ut[rb0 + cho];
        acc0 = __builtin_amdgcn_mfma_f32_32x32x16_bf16(a0[kb], b0, acc0, 0, 0, 0);
        bsh8 b1 = *(const bsh8*)&Ut[rb1 + cho];
        acc1 = __builtin_amdgcn_mfma_f32_32x32x16_bf16(a0[kb], b1, acc1, 0, 0, 0);
      }
      #pragma unroll
      for (int kb = 0; kb < 5; ++kb) { a0[kb] = a1[kb]; a1[kb] = a2[kb]; }
    }

    // ---- store: D col = l31 -> p, row o = (r&3) + 8*(r>>2) + 4*half ----
    const int p = p0 + wbase + l31;
    #pragma unroll
    for (int r = 0; r < 16; ++r) {
      int o = (r & 3) + 8 * (r >> 2) + 4 * half;
      size_t base = ((size_t)(b * COUT_ + o) * HOUT_ + xo) * WOUT_;
      if (p < WOUT_)
        __builtin_nontemporal_store(acc0[r], &out[base + p]);
      if (p + 32 < WOUT_)
        __builtin_nontemporal_store(acc1[r], &out[base + p + 32]);
    }
  }
}

extern "C" void kernel_launch(void* const* d_in, const int* in_sizes, int n_in,
                              void* d_out, int out_size, void* d_ws, size_t ws_size,
                              hipStream_t stream) {
  const float* x        = (const float*)d_in[0];
  const int*   psi_idx  = (const int*)d_in[1];
  const float* psi_vals = (const float*)d_in[2];
  const float* weight   = (const float*)d_in[3];
  float* out = (float*)d_out;
  unsigned short* Cg = (unsigned short*)d_ws;   // 361*2560*8 bf16 = 14.8 MB

  coeff_kernel<<<dim3(HOUT_), 256, 0, stream>>>(psi_idx, psi_vals, weight, Cg);
  disco_main_kernel<<<dim3(4 * HOUT_), 256, 0, stream>>>(x, Cg, out);
}

// Round 12
// 87.150 us; speedup vs baseline: 2.2764x; 2.2764x over previous
//
#include <hip/hip_runtime.h>
#include <hip/hip_bf16.h>

// ---- problem constants (match reference) ----
#define HIN   721
#define WIN   1440
#define HOUT_ 361
#define WOUT_ 720
#define NB    4
#define CIN_  8
#define COUT_ 32
#define KT    9
#define NNZ_  32
// derived: PSCALE = 2, base_row(x) = 2x exactly, cols in [0,16)
// q = c*10 + 2s + e  (80 values), j = col>>1 (8 values)

typedef short  bsh8   __attribute__((ext_vector_type(8)));   // 8 bf16 (4 VGPR) MFMA frag
typedef float  f32x16 __attribute__((ext_vector_type(16)));  // 32x32 MFMA acc
typedef unsigned int u32x4 __attribute__((ext_vector_type(4)));

static __device__ __forceinline__ unsigned short f2bf(float f) {
  unsigned u = __builtin_bit_cast(unsigned, f);
  u += 0x7fffu + ((u >> 16) & 1u);      // RNE
  return (unsigned short)(u >> 16);
}

static __device__ __forceinline__ unsigned pack2(float a, float b) {
  __hip_bfloat162 h = __float22bfloat162_rn(make_float2(a, b));
  unsigned u; __builtin_memcpy(&u, &h, 4);
  return u;                              // a -> low 16, b -> high 16
}

// =====================================================================
// K1: build combined coefficients — slim-LDS version (R11, kept):
// 45.4KB -> 3 blocks/CU -> all 361 blocks co-resident in ONE round
// (was 95KB -> 1 block/CU -> 2 serial rounds).
//  - Cl stored as bf16 (identical rounding: conversion moved from
//    writeback to combine-write), stride 83 u16.
//  - weight read direct from global (9 floats/thread, once).
// =====================================================================
__global__ __launch_bounds__(256, 3) void coeff_kernel(
    const int*   __restrict__ psi_idx,
    const float* __restrict__ psi_vals,
    const float* __restrict__ weight,
    unsigned short* __restrict__ Cg)
{
  __shared__ unsigned short Cl16[256 * 83];   // 42496 B
  __shared__ float S[KT][80];                 // 2880 B

  const int x = blockIdx.x, tid = threadIdx.x;

  for (int i = tid; i < KT * 80; i += 256) ((float*)S)[i] = 0.f;
  __syncthreads();

  for (int i = tid; i < KT * NNZ_; i += 256) {   // scatter all 288 taps
    int k = i >> 5, n = i & 31;
    int gi  = (k * HOUT_ + x) * NNZ_ + n;
    int idx = psi_idx[gi];
    int r   = idx / WIN;
    int col = idx - r * WIN;               // in [0,16)
    int s   = r - 2 * x + 2;               // in [0,4] after reference clip
    int slot = (s * 2 + (col & 1)) * 8 + (col >> 1);
    atomicAdd(&S[k][slot], psi_vals[gi]);
  }

  // thread (o = tid>>3, c = tid&7) reads its own 9 weights from global
  float w[KT];
  #pragma unroll
  for (int k = 0; k < KT; ++k) w[k] = weight[tid * KT + k];
  __syncthreads();

  { // dense combine, bf16 write
    unsigned short* seg = &Cl16[tid * 83];
    #pragma unroll
    for (int slot = 0; slot < 80; ++slot) {
      float acc = 0.f;
      #pragma unroll
      for (int k = 0; k < KT; ++k) acc += w[k] * S[k][slot];
      seg[slot] = f2bf(acc);
    }
  }
  __syncthreads();

  // writeback as 16B chunks: Cg[((x*8+j)*10+qb)*32+o][qi0..7]
  for (int chunk = tid; chunk < 8 * 10 * 32; chunk += 256) {
    int j   = chunk / 320;
    int rem = chunk - j * 320;
    int qb  = rem >> 5, o = rem & 31;
    u32x4 pack;
    #pragma unroll
    for (int h = 0; h < 4; ++h) {
      int q0 = qb * 8 + 2 * h;
      int c0 = q0 / 10, ql0 = q0 - c0 * 10;
      int q1 = q0 + 1;
      int c1 = q1 / 10, ql1 = q1 - c1 * 10;
      unsigned lo = Cl16[(o * CIN_ + c0) * 83 + ql0 * 8 + j];
      unsigned hi = Cl16[(o * CIN_ + c1) * 83 + ql1 * 8 + j];
      pack[h] = lo | (hi << 16);
    }
    *(u32x4*)&Cg[((size_t)x * 2560 + (size_t)((j * 10 + qb) * 32 + o)) * 8] = pack;
  }
}

// =====================================================================
// K2: main compute — EXACT R8 structure (best measured: 93.3us graph).
// R11 lesson: fusing pt tiles into fewer/longer blocks stretched x's
// cache-reuse distance (FETCH 75->223MB, L3 hit collapse) — the small
// 4332-block granularity IS the x-locality mechanism. Do not fuse.
//  - PB=256, 2 acc/wave; RST=176 no-swizzle (48 mod 128 walk -> b128
//    reads at the 8-dword/bank floor); rowpair b128 writes ~2-way.
//  - depth-2 A-frag prefetch; j=0/1 frags issued before staging.
//  - LDS 264*176 = 46464B -> 3 blocks/CU.
// =====================================================================
#define PB   256
#define ROWS 264            // max row read = 262
#define RST  176            // 176 mod 128 = 48 -> b128 reads at bank floor

__global__ __launch_bounds__(256, 3) void disco_main_kernel(
    const float* __restrict__ x,
    const unsigned short* __restrict__ Cg,
    float* __restrict__ out)
{
  __shared__ __align__(16) unsigned char Ut[ROWS * RST];  // 46464 B

  // ---- bijective XCD-chunked decode (nwg = 4332 = 8*541 + 4, m204) ----
  const int g   = blockIdx.x;
  const int xcd = g & 7, lin = g >> 3;
  const int swz = (xcd < 4) ? xcd * 542 + lin : 4 * 542 + (xcd - 4) * 541 + lin;
  const int xo  = swz / 12;
  const int rem = swz - xo * 12;
  const int pt  = rem % 3;          // 0..2
  const int b   = rem / 3;          // 0..3
  const int p0  = pt * PB;
  const int tid = threadIdx.x;

  const int lane = tid & 63;
  const int wv   = tid >> 6;        // 0..3: 64-wide p slice
  const int half = lane >> 5;       // k-slice half (chunk parity)
  const int l31  = lane & 31;
  const int wbase = wv * 64;

  const unsigned short* cgx = Cg + (size_t)xo * 2560 * 8
                                 + (size_t)(half * 32 + l31) * 8;

  // ---- issue j=0 and j=1 A-frag loads first: overlap staging + barrier ----
  bsh8 a0[5], a1[5];
  #pragma unroll
  for (int kb = 0; kb < 5; ++kb) a0[kb] = *(const bsh8*)&cgx[kb * 512];
  #pragma unroll
  for (int kb = 0; kb < 5; ++kb) a1[kb] = *(const bsh8*)&cgx[2560 + kb * 512];

  const float* xb = x + (size_t)b * (CIN_ * HIN * WIN);

  int rr[5];
  #pragma unroll
  for (int s = 0; s < 5; ++s) {
    int r = 2 * xo + s - 2;
    rr[s] = r < 0 ? 0 : (r > HIN - 1 ? HIN - 1 : r);
  }

  // ---- stage Ut: 1320 units (ch = u/132, rp = u%132 -> rows 2rp,2rp+1) ----
  // unit: 4 float4 loads (q-pairs 4ch+m, m=0..3) -> 2x ds_write_b128
  #pragma unroll
  for (int bp = 0; bp < 2; ++bp) {
    float4 v0[4], v1[4];
    const int uA = tid + (2 * bp) * 256, uB = uA + 256;
    const int chA = uA / 132, rpA = uA - chA * 132;
    const int chB = uB / 132, rpB = uB - chB * 132;
    int cwA = p0 + 2 * rpA; if (cwA >= WOUT_) cwA -= WOUT_;
    int cwB = p0 + 2 * rpB; if (cwB >= WOUT_) cwB -= WOUT_;
    #pragma unroll
    for (int m = 0; m < 4; ++m) {
      int qpA = 4 * chA + m, cA = (qpA * 205) >> 10, sA = qpA - cA * 5;
      v0[m] = *(const float4*)&xb[(size_t)(cA * HIN + rr[sA]) * WIN + 2 * cwA];
      int qpB = 4 * chB + m, cB = (qpB * 205) >> 10, sB = qpB - cB * 5;
      v1[m] = *(const float4*)&xb[(size_t)(cB * HIN + rr[sB]) * WIN + 2 * cwB];
    }
    u32x4 lo, hi;
    #pragma unroll
    for (int m = 0; m < 4; ++m) { lo[m] = pack2(v0[m].x, v0[m].y); hi[m] = pack2(v0[m].z, v0[m].w); }
    int byte0 = (2 * rpA) * RST + chA * 16;
    *(u32x4*)&Ut[byte0]       = lo;
    *(u32x4*)&Ut[byte0 + RST] = hi;
    #pragma unroll
    for (int m = 0; m < 4; ++m) { lo[m] = pack2(v1[m].x, v1[m].y); hi[m] = pack2(v1[m].z, v1[m].w); }
    byte0 = (2 * rpB) * RST + chB * 16;
    *(u32x4*)&Ut[byte0]       = lo;
    *(u32x4*)&Ut[byte0 + RST] = hi;
  }
  { // unit pass 5 (u in [1024,1280)) + tail (u in [1280,1320), tid < 40)
    const int uA = tid + 1024;
    const int chA = uA / 132, rpA = uA - chA * 132;
    int cwA = p0 + 2 * rpA; if (cwA >= WOUT_) cwA -= WOUT_;
    float4 v0[4], v1[4];
    int chB = 0, rpB = 0;
    const bool tail = tid < 40;
    if (tail) {
      const int uB = tid + 1280;
      chB = uB / 132; rpB = uB - chB * 132;
    }
    int cwB = p0 + 2 * rpB; if (cwB >= WOUT_) cwB -= WOUT_;
    #pragma unroll
    for (int m = 0; m < 4; ++m) {
      int qpA = 4 * chA + m, cA = (qpA * 205) >> 10, sA = qpA - cA * 5;
      v0[m] = *(const float4*)&xb[(size_t)(cA * HIN + rr[sA]) * WIN + 2 * cwA];
    }
    if (tail) {
      #pragma unroll
      for (int m = 0; m < 4; ++m) {
        int qpB = 4 * chB + m, cB = (qpB * 205) >> 10, sB = qpB - cB * 5;
        v1[m] = *(const float4*)&xb[(size_t)(cB * HIN + rr[sB]) * WIN + 2 * cwB];
      }
    }
    u32x4 lo, hi;
    #pragma unroll
    for (int m = 0; m < 4; ++m) { lo[m] = pack2(v0[m].x, v0[m].y); hi[m] = pack2(v0[m].z, v0[m].w); }
    int byte0 = (2 * rpA) * RST + chA * 16;
    *(u32x4*)&Ut[byte0]       = lo;
    *(u32x4*)&Ut[byte0 + RST] = hi;
    if (tail) {
      #pragma unroll
      for (int m = 0; m < 4; ++m) { lo[m] = pack2(v1[m].x, v1[m].y); hi[m] = pack2(v1[m].z, v1[m].w); }
      byte0 = (2 * rpB) * RST + chB * 16;
      *(u32x4*)&Ut[byte0]       = lo;
      *(u32x4*)&Ut[byte0 + RST] = hi;
    }
  }
  __syncthreads();

  // ---- MFMA phase: wave -> 32(o) x 64(p), j unrolled, depth-2 prefetch ----
  f32x16 acc0 = {};
  f32x16 acc1 = {};

  #pragma unroll
  for (int j = 0; j < 8; ++j) {
    bsh8 a2[5];
    if (j < 6) {
      #pragma unroll
      for (int kb = 0; kb < 5; ++kb)
        a2[kb] = *(const bsh8*)&cgx[(j + 2) * 2560 + kb * 512];
    }
    const int row0 = wbase + l31 + j;
    const int rb0  = row0 * RST;
    const int rb1  = rb0 + 32 * RST;
    #pragma unroll
    for (int kb = 0; kb < 5; ++kb) {
      const int cho = (2 * kb + half) * 16;
      bsh8 b0 = *(const bsh8*)&Ut[rb0 + cho];
      acc0 = __builtin_amdgcn_mfma_f32_32x32x16_bf16(a0[kb], b0, acc0, 0, 0, 0);
      bsh8 b1 = *(const bsh8*)&Ut[rb1 + cho];
      acc1 = __builtin_amdgcn_mfma_f32_32x32x16_bf16(a0[kb], b1, acc1, 0, 0, 0);
    }
    #pragma unroll
    for (int kb = 0; kb < 5; ++kb) { a0[kb] = a1[kb]; a1[kb] = a2[kb]; }
  }

  // ---- store: D col = l31 -> p, row o = (r&3) + 8*(r>>2) + 4*half ----
  const int p = p0 + wbase + l31;
  #pragma unroll
  for (int r = 0; r < 16; ++r) {
    int o = (r & 3) + 8 * (r >> 2) + 4 * half;
    size_t base = ((size_t)(b * COUT_ + o) * HOUT_ + xo) * WOUT_;
    if (p < WOUT_)
      __builtin_nontemporal_store(acc0[r], &out[base + p]);
    if (p + 32 < WOUT_)
      __builtin_nontemporal_store(acc1[r], &out[base + p + 32]);
  }
}

extern "C" void kernel_launch(void* const* d_in, const int* in_sizes, int n_in,
                              void* d_out, int out_size, void* d_ws, size_t ws_size,
                              hipStream_t stream) {
  const float* x        = (const float*)d_in[0];
  const int*   psi_idx  = (const int*)d_in[1];
  const float* psi_vals = (const float*)d_in[2];
  const float* weight   = (const float*)d_in[3];
  float* out = (float*)d_out;
  unsigned short* Cg = (unsigned short*)d_ws;   // 361*2560*8 bf16 = 14.8 MB

  coeff_kernel<<<dim3(HOUT_), 256, 0, stream>>>(psi_idx, psi_vals, weight, Cg);
  disco_main_kernel<<<dim3(3 * NB * HOUT_), 256, 0, stream>>>(x, Cg, out);
}

// Round 13
// 86.260 us; speedup vs baseline: 2.2999x; 1.0103x over previous
//
#include <hip/hip_runtime.h>
#include <hip/hip_bf16.h>

// ---- problem constants (match reference) ----
#define HIN   721
#define WIN   1440
#define HOUT_ 361
#define WOUT_ 720
#define NB    4
#define CIN_  8
#define COUT_ 32
#define KT    9
#define NNZ_  32
// derived: PSCALE = 2, base_row(x) = 2x exactly, cols in [0,16)
// q = c*10 + 2s + e  (80 values), j = col>>1 (8 values)

typedef short  bsh8   __attribute__((ext_vector_type(8)));   // 8 bf16 (4 VGPR) MFMA frag
typedef float  f32x16 __attribute__((ext_vector_type(16)));  // 32x32 MFMA acc
typedef unsigned int u32x4 __attribute__((ext_vector_type(4)));

static __device__ __forceinline__ unsigned short f2bf(float f) {
  unsigned u = __builtin_bit_cast(unsigned, f);
  u += 0x7fffu + ((u >> 16) & 1u);      // RNE
  return (unsigned short)(u >> 16);
}

static __device__ __forceinline__ unsigned pack2(float a, float b) {
  __hip_bfloat162 h = __float22bfloat162_rn(make_float2(a, b));
  unsigned u; __builtin_memcpy(&u, &h, 4);
  return u;                              // a -> low 16, b -> high 16
}

// =====================================================================
// K1: build combined coefficients — slim-LDS (45.4KB -> 3 blocks/CU,
// all 361 blocks co-resident; R12 verified −6us).
// =====================================================================
__global__ __launch_bounds__(256, 3) void coeff_kernel(
    const int*   __restrict__ psi_idx,
    const float* __restrict__ psi_vals,
    const float* __restrict__ weight,
    unsigned short* __restrict__ Cg)
{
  __shared__ unsigned short Cl16[256 * 83];   // 42496 B
  __shared__ float S[KT][80];                 // 2880 B

  const int x = blockIdx.x, tid = threadIdx.x;

  for (int i = tid; i < KT * 80; i += 256) ((float*)S)[i] = 0.f;
  __syncthreads();

  for (int i = tid; i < KT * NNZ_; i += 256) {   // scatter all 288 taps
    int k = i >> 5, n = i & 31;
    int gi  = (k * HOUT_ + x) * NNZ_ + n;
    int idx = psi_idx[gi];
    int r   = idx / WIN;
    int col = idx - r * WIN;               // in [0,16)
    int s   = r - 2 * x + 2;               // in [0,4] after reference clip
    int slot = (s * 2 + (col & 1)) * 8 + (col >> 1);
    atomicAdd(&S[k][slot], psi_vals[gi]);
  }

  // thread (o = tid>>3, c = tid&7) reads its own 9 weights from global
  float w[KT];
  #pragma unroll
  for (int k = 0; k < KT; ++k) w[k] = weight[tid * KT + k];
  __syncthreads();

  { // dense combine, bf16 write
    unsigned short* seg = &Cl16[tid * 83];
    #pragma unroll
    for (int slot = 0; slot < 80; ++slot) {
      float acc = 0.f;
      #pragma unroll
      for (int k = 0; k < KT; ++k) acc += w[k] * S[k][slot];
      seg[slot] = f2bf(acc);
    }
  }
  __syncthreads();

  // writeback as 16B chunks: Cg[((x*8+j)*10+qb)*32+o][qi0..7]
  for (int chunk = tid; chunk < 8 * 10 * 32; chunk += 256) {
    int j   = chunk / 320;
    int rem = chunk - j * 320;
    int qb  = rem >> 5, o = rem & 31;
    u32x4 pack;
    #pragma unroll
    for (int h = 0; h < 4; ++h) {
      int q0 = qb * 8 + 2 * h;
      int c0 = q0 / 10, ql0 = q0 - c0 * 10;
      int q1 = q0 + 1;
      int c1 = q1 / 10, ql1 = q1 - c1 * 10;
      unsigned lo = Cl16[(o * CIN_ + c0) * 83 + ql0 * 8 + j];
      unsigned hi = Cl16[(o * CIN_ + c1) * 83 + ql1 * 8 + j];
      pack[h] = lo | (hi << 16);
    }
    *(u32x4*)&Cg[((size_t)x * 2560 + (size_t)((j * 10 + qb) * 32 + o)) * 8] = pack;
  }
}

// =====================================================================
// K2: main compute. R12/R8 body + cross-j software pipeline:
//  - B-frag depth-1 prefetch: j+1's 10 ds_read_b128 issued BEFORE j's
//    MFMA cluster -> MFMAs never wait on same-iteration LDS latency.
//  - A-frag 2-slot rotation afr[j&1] (static idx): prologue covers j=0,1
//    (in flight during staging); in-loop reload for j+2.
//  - s_setprio(1) around MFMA cluster (T5: 3 staggered blocks/CU give
//    wave role-diversity, the regime where setprio pays).
//  - geometry unchanged: PB=256, RST=176 bank-floor layout, 3 blocks/CU.
//  Register budget: acc 32 + afr 40 + bcur/bnxt 80 + misc ~15 = ~167
//  (< 170 cap for 3 waves/SIMD; launch_bounds(256,3) enforces).
// =====================================================================
#define PB   256
#define ROWS 264            // max row read = 262
#define RST  176            // 176 mod 128 = 48 -> b128 reads at bank floor

__global__ __launch_bounds__(256, 3) void disco_main_kernel(
    const float* __restrict__ x,
    const unsigned short* __restrict__ Cg,
    float* __restrict__ out)
{
  __shared__ __align__(16) unsigned char Ut[ROWS * RST];  // 46464 B

  // ---- bijective XCD-chunked decode (nwg = 4332 = 8*541 + 4, m204) ----
  const int g   = blockIdx.x;
  const int xcd = g & 7, lin = g >> 3;
  const int swz = (xcd < 4) ? xcd * 542 + lin : 4 * 542 + (xcd - 4) * 541 + lin;
  const int xo  = swz / 12;
  const int rem = swz - xo * 12;
  const int pt  = rem % 3;          // 0..2
  const int b   = rem / 3;          // 0..3
  const int p0  = pt * PB;
  const int tid = threadIdx.x;

  const int lane = tid & 63;
  const int wv   = tid >> 6;        // 0..3: 64-wide p slice
  const int half = lane >> 5;       // k-slice half (chunk parity)
  const int l31  = lane & 31;
  const int wbase = wv * 64;

  const unsigned short* cgx = Cg + (size_t)xo * 2560 * 8
                                 + (size_t)(half * 32 + l31) * 8;

  // ---- A-frags for j=0 and j=1 issued first: overlap staging + barrier ----
  bsh8 afr[2][5];
  #pragma unroll
  for (int kb = 0; kb < 5; ++kb) afr[0][kb] = *(const bsh8*)&cgx[kb * 512];
  #pragma unroll
  for (int kb = 0; kb < 5; ++kb) afr[1][kb] = *(const bsh8*)&cgx[2560 + kb * 512];

  const float* xb = x + (size_t)b * (CIN_ * HIN * WIN);

  int rr[5];
  #pragma unroll
  for (int s = 0; s < 5; ++s) {
    int r = 2 * xo + s - 2;
    rr[s] = r < 0 ? 0 : (r > HIN - 1 ? HIN - 1 : r);
  }

  // ---- stage Ut: 1320 units (ch = u/132, rp = u%132 -> rows 2rp,2rp+1) ----
  // unit: 4 float4 loads (q-pairs 4ch+m, m=0..3) -> 2x ds_write_b128
  #pragma unroll
  for (int bp = 0; bp < 2; ++bp) {
    float4 v0[4], v1[4];
    const int uA = tid + (2 * bp) * 256, uB = uA + 256;
    const int chA = uA / 132, rpA = uA - chA * 132;
    const int chB = uB / 132, rpB = uB - chB * 132;
    int cwA = p0 + 2 * rpA; if (cwA >= WOUT_) cwA -= WOUT_;
    int cwB = p0 + 2 * rpB; if (cwB >= WOUT_) cwB -= WOUT_;
    #pragma unroll
    for (int m = 0; m < 4; ++m) {
      int qpA = 4 * chA + m, cA = (qpA * 205) >> 10, sA = qpA - cA * 5;
      v0[m] = *(const float4*)&xb[(size_t)(cA * HIN + rr[sA]) * WIN + 2 * cwA];
      int qpB = 4 * chB + m, cB = (qpB * 205) >> 10, sB = qpB - cB * 5;
      v1[m] = *(const float4*)&xb[(size_t)(cB * HIN + rr[sB]) * WIN + 2 * cwB];
    }
    u32x4 lo, hi;
    #pragma unroll
    for (int m = 0; m < 4; ++m) { lo[m] = pack2(v0[m].x, v0[m].y); hi[m] = pack2(v0[m].z, v0[m].w); }
    int byte0 = (2 * rpA) * RST + chA * 16;
    *(u32x4*)&Ut[byte0]       = lo;
    *(u32x4*)&Ut[byte0 + RST] = hi;
    #pragma unroll
    for (int m = 0; m < 4; ++m) { lo[m] = pack2(v1[m].x, v1[m].y); hi[m] = pack2(v1[m].z, v1[m].w); }
    byte0 = (2 * rpB) * RST + chB * 16;
    *(u32x4*)&Ut[byte0]       = lo;
    *(u32x4*)&Ut[byte0 + RST] = hi;
  }
  { // unit pass 5 (u in [1024,1280)) + tail (u in [1280,1320), tid < 40)
    const int uA = tid + 1024;
    const int chA = uA / 132, rpA = uA - chA * 132;
    int cwA = p0 + 2 * rpA; if (cwA >= WOUT_) cwA -= WOUT_;
    float4 v0[4], v1[4];
    int chB = 0, rpB = 0;
    const bool tail = tid < 40;
    if (tail) {
      const int uB = tid + 1280;
      chB = uB / 132; rpB = uB - chB * 132;
    }
    int cwB = p0 + 2 * rpB; if (cwB >= WOUT_) cwB -= WOUT_;
    #pragma unroll
    for (int m = 0; m < 4; ++m) {
      int qpA = 4 * chA + m, cA = (qpA * 205) >> 10, sA = qpA - cA * 5;
      v0[m] = *(const float4*)&xb[(size_t)(cA * HIN + rr[sA]) * WIN + 2 * cwA];
    }
    if (tail) {
      #pragma unroll
      for (int m = 0; m < 4; ++m) {
        int qpB = 4 * chB + m, cB = (qpB * 205) >> 10, sB = qpB - cB * 5;
        v1[m] = *(const float4*)&xb[(size_t)(cB * HIN + rr[sB]) * WIN + 2 * cwB];
      }
    }
    u32x4 lo, hi;
    #pragma unroll
    for (int m = 0; m < 4; ++m) { lo[m] = pack2(v0[m].x, v0[m].y); hi[m] = pack2(v0[m].z, v0[m].w); }
    int byte0 = (2 * rpA) * RST + chA * 16;
    *(u32x4*)&Ut[byte0]       = lo;
    *(u32x4*)&Ut[byte0 + RST] = hi;
    if (tail) {
      #pragma unroll
      for (int m = 0; m < 4; ++m) { lo[m] = pack2(v1[m].x, v1[m].y); hi[m] = pack2(v1[m].z, v1[m].w); }
      byte0 = (2 * rpB) * RST + chB * 16;
      *(u32x4*)&Ut[byte0]       = lo;
      *(u32x4*)&Ut[byte0 + RST] = hi;
    }
  }
  __syncthreads();

  // ---- MFMA phase: cross-j pipelined ----
  f32x16 acc0 = {};
  f32x16 acc1 = {};

  bsh8 bc0[5], bc1[5];                 // current-j B-frags
  {
    const int rb0 = (wbase + l31) * RST;
    const int rb1 = rb0 + 32 * RST;
    #pragma unroll
    for (int kb = 0; kb < 5; ++kb) {
      const int cho = (2 * kb + half) * 16;
      bc0[kb] = *(const bsh8*)&Ut[rb0 + cho];
      bc1[kb] = *(const bsh8*)&Ut[rb1 + cho];
    }
  }

  #pragma unroll
  for (int j = 0; j < 8; ++j) {
    bsh8 bn0[5], bn1[5];
    if (j < 7) {                       // prefetch j+1's B-frags first
      const int rb0 = (wbase + l31 + j + 1) * RST;
      const int rb1 = rb0 + 32 * RST;
      #pragma unroll
      for (int kb = 0; kb < 5; ++kb) {
        const int cho = (2 * kb + half) * 16;
        bn0[kb] = *(const bsh8*)&Ut[rb0 + cho];
        bn1[kb] = *(const bsh8*)&Ut[rb1 + cho];
      }
    }
    __builtin_amdgcn_s_setprio(1);
    #pragma unroll
    for (int kb = 0; kb < 5; ++kb) {
      acc0 = __builtin_amdgcn_mfma_f32_32x32x16_bf16(afr[j & 1][kb], bc0[kb], acc0, 0, 0, 0);
      acc1 = __builtin_amdgcn_mfma_f32_32x32x16_bf16(afr[j & 1][kb], bc1[kb], acc1, 0, 0, 0);
    }
    __builtin_amdgcn_s_setprio(0);
    if (j < 6) {                       // reload this slot with j+2's A-frags
      #pragma unroll
      for (int kb = 0; kb < 5; ++kb)
        afr[j & 1][kb] = *(const bsh8*)&cgx[(j + 2) * 2560 + kb * 512];
    }
    #pragma unroll
    for (int kb = 0; kb < 5; ++kb) { bc0[kb] = bn0[kb]; bc1[kb] = bn1[kb]; }
  }

  // ---- store: D col = l31 -> p, row o = (r&3) + 8*(r>>2) + 4*half ----
  const int p = p0 + wbase + l31;
  #pragma unroll
  for (int r = 0; r < 16; ++r) {
    int o = (r & 3) + 8 * (r >> 2) + 4 * half;
    size_t base = ((size_t)(b * COUT_ + o) * HOUT_ + xo) * WOUT_;
    if (p < WOUT_)
      __builtin_nontemporal_store(acc0[r], &out[base + p]);
    if (p + 32 < WOUT_)
      __builtin_nontemporal_store(acc1[r], &out[base + p + 32]);
  }
}

extern "C" void kernel_launch(void* const* d_in, const int* in_sizes, int n_in,
                              void* d_out, int out_size, void* d_ws, size_t ws_size,
                              hipStream_t stream) {
  const float* x        = (const float*)d_in[0];
  const int*   psi_idx  = (const int*)d_in[1];
  const float* psi_vals = (const float*)d_in[2];
  const float* weight   = (const float*)d_in[3];
  float* out = (float*)d_out;
  unsigned short* Cg = (unsigned short*)d_ws;   // 361*2560*8 bf16 = 14.8 MB

  coeff_kernel<<<dim3(HOUT_), 256, 0, stream>>>(psi_idx, psi_vals, weight, Cg);
  disco_main_kernel<<<dim3(3 * NB * HOUT_), 256, 0, stream>>>(x, Cg, out);
}